// Round 1
// baseline (716.022 us; speedup 1.0000x reference)
//
#include <hip/hip_runtime.h>
#include <hip/hip_bf16.h>
#include <stdint.h>

#define BATCH 16
#define CDIM  512
#define DDIM  4096
#define SPART ((size_t)BATCH * CDIM * CDIM)   // elements per split-K partial of S

typedef short bf16x8 __attribute__((ext_vector_type(8)));
typedef float f32x4  __attribute__((ext_vector_type(4)));

static __device__ __forceinline__ uint32_t pack2bf(float lo, float hi) {
  __hip_bfloat162 h2 = __float22bfloat162_rn(make_float2(lo, hi));
  uint32_t u; __builtin_memcpy(&u, &h2, 4); return u;
}

// ---------------------------------------------------------------------------
// Phase 1: S_part[kz][b][c][e] = (1/64) * sum_{d in chunk kz} Q[b][c][d]*K[b][e][d]
// 256x256 tile (halves HBM re-reads vs 128^2: 1.07GB -> 536MB), 8 waves (2x4),
// BK=32, double-buffered LDS, ONE barrier per K-step, register prefetch issued
// after the barrier so HBM latency hides under the MFMA phase. Split-K x4
// (chunks of 1024) -> grid 2*2*64 = 256 blocks = 1 block/CU.
// LDS row = 32 bf16 = 64 B; swizzle f(r) = (r ^ (r>>2)) & 3 applied on BOTH
// write and read gives 2-way (free) access on each side.
// ---------------------------------------------------------------------------
__global__ __launch_bounds__(512, 2) void gemm_qk(const float* __restrict__ Q,
                                                  const float* __restrict__ K,
                                                  float* __restrict__ S) {
  __shared__ __align__(16) char sA[2][16384];   // 256 rows x 64 B
  __shared__ __align__(16) char sB[2][16384];
  const int zz   = blockIdx.z;
  const int kz   = zz & 3;           // split-K chunk
  const int b    = zz >> 2;
  const int c0   = blockIdx.y * 256;
  const int e0   = blockIdx.x * 256;
  const int t    = threadIdx.x;
  const int lane = t & 63;
  const int wave = t >> 6;           // 0..7
  const int wm = wave & 1, wn = wave >> 1;   // 2 x 4 wave grid
  const int l15 = lane & 15, quad = lane >> 4;

  const float* Qb = Q + (size_t)b * CDIM * DDIM;
  const float* Kb = K + (size_t)b * CDIM * DDIM;

  f32x4 acc[8][4];
  const f32x4 zero = {0.f, 0.f, 0.f, 0.f};
#pragma unroll
  for (int i = 0; i < 8; i++)
#pragma unroll
    for (int j = 0; j < 4; j++) acc[i][j] = zero;

  const int h  = t & 7;     // float4 index within 32-float row
  const int rb = t >> 3;    // row base 0..63 (4 passes of 64 rows)
  const int dlo = kz * 1024;

  float4 qa[4], ka[4];
#define QK_LOADS(d0)                                                              \
  do {                                                                            \
    _Pragma("unroll")                                                             \
    for (int p = 0; p < 4; p++) {                                                 \
      int r = rb + (p << 6);                                                      \
      qa[p] = *(const float4*)(Qb + (size_t)(c0 + r) * DDIM + (d0) + (h << 2));   \
      ka[p] = *(const float4*)(Kb + (size_t)(e0 + r) * DDIM + (d0) + (h << 2));   \
    }                                                                             \
  } while (0)

  QK_LOADS(dlo);
  int cur = 0;
#pragma unroll 2
  for (int s = 0; s < 32; s++) {
    // write phase: convert prefetched fp32 -> bf16 into LDS[cur]
#pragma unroll
    for (int p = 0; p < 4; p++) {
      int r   = rb + (p << 6);
      int f   = (r ^ (r >> 2)) & 3;
      int off = r * 64 + (((h >> 1) ^ f) << 4) + ((h & 1) << 3);
      *(uint2*)(sA[cur] + off) = make_uint2(pack2bf(qa[p].x, qa[p].y), pack2bf(qa[p].z, qa[p].w));
      *(uint2*)(sB[cur] + off) = make_uint2(pack2bf(ka[p].x, ka[p].y), pack2bf(ka[p].z, ka[p].w));
    }
    __syncthreads();
    // issue next step's loads NOW: they stay in flight across the MFMA phase
    // and are vmcnt-consumed by next iteration's write phase (no barrier drain
    // cost: by the next barrier they are already at vmcnt 0).
    if (s + 1 < 32) QK_LOADS(dlo + ((s + 1) << 5));
    bf16x8 af[8], bfr[4];
#pragma unroll
    for (int mi = 0; mi < 8; mi++) {
      int r = wm * 128 + mi * 16 + l15;
      int f = (r ^ (r >> 2)) & 3;
      af[mi] = *(const bf16x8*)(sA[cur] + r * 64 + ((quad ^ f) << 4));
    }
#pragma unroll
    for (int ni = 0; ni < 4; ni++) {
      int r = wn * 64 + ni * 16 + l15;
      int f = (r ^ (r >> 2)) & 3;
      bfr[ni] = *(const bf16x8*)(sB[cur] + r * 64 + ((quad ^ f) << 4));
    }
#pragma unroll
    for (int mi = 0; mi < 8; mi++)
#pragma unroll
      for (int ni = 0; ni < 4; ni++)
        acc[mi][ni] = __builtin_amdgcn_mfma_f32_16x16x32_bf16(af[mi], bfr[ni], acc[mi][ni], 0, 0, 0);
    cur ^= 1;
    // no second barrier needed: next write goes to the OTHER buffer, and every
    // wave's reads of buffer X complete (lgkmcnt before MFMA use) before that
    // wave's next write, which precedes the barrier separating it from the
    // conflicting cross-wave write two steps later.
  }
#undef QK_LOADS

  float* Sb = S + (size_t)kz * SPART + (size_t)b * CDIM * CDIM;
#pragma unroll
  for (int mi = 0; mi < 8; mi++)
#pragma unroll
    for (int ni = 0; ni < 4; ni++) {
      int col = e0 + wn * 64 + ni * 16 + l15;
#pragma unroll
      for (int reg = 0; reg < 4; reg++) {
        int row = c0 + wm * 128 + mi * 16 + quad * 4 + reg;
        Sb[(size_t)row * CDIM + col] = acc[mi][ni][reg] * 0.015625f;  // 1/64 exact
      }
    }
}

// ---------------------------------------------------------------------------
// Phase 2a: row softmax of (sum of 4 S partials) -> P_a[b][c][e] (bf16).
// Now ALSO writes the reduced sum Ssum (fp32) so softmax_cols reads 17 MB
// once instead of 67 MB of scattered partials.
// ---------------------------------------------------------------------------
__global__ __launch_bounds__(256) void softmax_rows(const float* __restrict__ S,
                                                    float* __restrict__ Ssum,
                                                    __hip_bfloat16* __restrict__ P) {
  const int row = blockIdx.x;  // b*512 + c
  const float* Sr = S + (size_t)row * CDIM;
  const int t = threadIdx.x;
  float v0 = (Sr[t] + Sr[t + SPART]) + (Sr[t + 2 * SPART] + Sr[t + 3 * SPART]);
  float v1 = (Sr[t + 256] + Sr[t + 256 + SPART]) +
             (Sr[t + 256 + 2 * SPART] + Sr[t + 256 + 3 * SPART]);
  Ssum[(size_t)row * CDIM + t]       = v0;
  Ssum[(size_t)row * CDIM + t + 256] = v1;
  float m = fmaxf(v0, v1);
#pragma unroll
  for (int off = 32; off > 0; off >>= 1) m = fmaxf(m, __shfl_down(m, off));
  __shared__ float red[8];
  if ((t & 63) == 0) red[t >> 6] = m;
  __syncthreads();
  m = fmaxf(fmaxf(red[0], red[1]), fmaxf(red[2], red[3]));
  float e0 = __expf(v0 - m), e1 = __expf(v1 - m);
  float s = e0 + e1;
#pragma unroll
  for (int off = 32; off > 0; off >>= 1) s += __shfl_down(s, off);
  if ((t & 63) == 0) red[4 + (t >> 6)] = s;
  __syncthreads();
  s = (red[4] + red[5]) + (red[6] + red[7]);
  float inv = 1.0f / s;
  P[(size_t)row * CDIM + t]       = __float2bfloat16(e0 * inv);
  P[(size_t)row * CDIM + t + 256] = __float2bfloat16(e1 * inv);
}

// ---------------------------------------------------------------------------
// Phase 2b: column softmax of Ssum -> P_b[b][e][c] (bf16).
// Block = (16 columns e) x (512 rows c), column data cached in LDS.
// Reads the pre-reduced Ssum: 1 load/element instead of 4 partials.
// ---------------------------------------------------------------------------
__global__ __launch_bounds__(256) void softmax_cols(const float* __restrict__ Ssum,
                                                    __hip_bfloat16* __restrict__ Pb) {
  __shared__ float col[512][17];
  __shared__ float red[16][17];
  __shared__ float invs[16];
  const int b  = blockIdx.y;
  const int e0 = blockIdx.x * 16;
  const int t  = threadIdx.x;
  const int ci = t & 15, ri = t >> 4;
  const float* Sb = Ssum + (size_t)b * CDIM * CDIM + e0;

  float pmax = -1e30f;
#pragma unroll 4
  for (int it = 0; it < 32; it++) {
    int row = ri + (it << 4);
    float v = Sb[(size_t)row * CDIM + ci];
    col[row][ci] = v;
    pmax = fmaxf(pmax, v);
  }
  red[ri][ci] = pmax;
  __syncthreads();
  float M = red[0][ci];
#pragma unroll
  for (int k = 1; k < 16; k++) M = fmaxf(M, red[k][ci]);
  float psum = 0.f;
#pragma unroll 4
  for (int it = 0; it < 32; it++) {
    int row = ri + (it << 4);
    float ev = __expf(col[row][ci] - M);
    col[row][ci] = ev;
    psum += ev;
  }
  __syncthreads();               // protect red reuse
  red[ri][ci] = psum;
  __syncthreads();
  if (ri == 0) {
    float s = 0.f;
#pragma unroll
    for (int k = 0; k < 16; k++) s += red[k][ci];
    invs[ci] = 1.0f / s;
  }
  __syncthreads();
  __hip_bfloat16* Prow = Pb + ((size_t)b * CDIM + e0) * CDIM;
#pragma unroll
  for (int re = 0; re < 16; re++) {
    float inv = invs[re];
    Prow[(size_t)re * CDIM + t]       = __float2bfloat16(col[t][re] * inv);
    Prow[(size_t)re * CDIM + t + 256] = __float2bfloat16(col[t + 256][re] * inv);
  }
}

// ---------------------------------------------------------------------------
// Phase 3: out[b][m][d] = sum_e P[b][m][e] * V[b][e][d]
// dir 0: P=P_a, V=x2 (K), out=out_A.  dir 1: P=P_b, V=x1 (Q), out=out_B.
// Changes vs previous round:
//  (a) V staging thread map (vg,dg) = ((t>>2)&7, ((t>>5)<<2)|(t&3)): every
//      16-lane quarter now writes all 8 XOR-granules (2-way = free) instead of
//      2 granules (16-way). Global loads stay 64B-line coalesced (lanes 0-3 =
//      64B contiguous). This was the measured 1.26e7 SQ_LDS_BANK_CONFLICT.
//  (b) register prefetch: next e-tile's 4 P uint4 + 8 V float4 loads are
//      issued right after the first barrier, so their latency hides under the
//      ds_read+MFMA phase instead of serializing per tile (MfmaUtil 15%).
// ---------------------------------------------------------------------------
__global__ __launch_bounds__(256) void gemm_pv(const __hip_bfloat16* __restrict__ PaAll,
                                               const __hip_bfloat16* __restrict__ PbAll,
                                               const float* __restrict__ X1,
                                               const float* __restrict__ X2,
                                               float* __restrict__ out) {
  __shared__ __align__(16) char sP[16384];
  __shared__ __align__(16) char sV[16384];
  const int zz  = blockIdx.z;
  const int dir = zz & 1, b = zz >> 1;
  const int m0  = blockIdx.y * 128;
  const int d0b = blockIdx.x * 128;
  const int t    = threadIdx.x;
  const int lane = t & 63, wave = t >> 6;
  const int wm = wave & 1, wn = wave >> 1;
  const int l15 = lane & 15, quad = lane >> 4;

  const uint16_t* P = (const uint16_t*)(dir ? PbAll : PaAll) + (size_t)b * CDIM * CDIM;
  const float*    V = (dir ? X1 : X2) + (size_t)b * CDIM * DDIM;
  float*          O = out + (size_t)dir * ((size_t)BATCH * CDIM * DDIM) + (size_t)b * CDIM * DDIM;

  f32x4 acc[4][4];
  const f32x4 zero = {0.f, 0.f, 0.f, 0.f};
#pragma unroll
  for (int i = 0; i < 4; i++)
#pragma unroll
    for (int j = 0; j < 4; j++) acc[i][j] = zero;

  const int cl = t >> 3, gs = t & 7;            // P staging: row, granule
  const int vg = (t >> 2) & 7;                  // V staging: e-octet (0..7)
  const int dg = ((t >> 5) << 2) | (t & 3);     // V staging: d-quad (0..31)

  uint4  pr[4];
  float4 vr[8];
#define PV_LOADS(eb)                                                             \
  do {                                                                           \
    _Pragma("unroll")                                                            \
    for (int j = 0; j < 4; j++) {                                                \
      int c  = cl + (j << 5);                                                    \
      int gl = gs ^ (c & 7);                                                     \
      pr[j] = *(const uint4*)(P + (size_t)(m0 + c) * CDIM + (eb) + (gl << 3));   \
    }                                                                            \
    const float* vb = V + (size_t)((eb) + (vg << 3)) * DDIM + d0b + (dg << 2);   \
    _Pragma("unroll")                                                            \
    for (int j = 0; j < 8; j++) vr[j] = *(const float4*)(vb + j * DDIM);         \
  } while (0)

  PV_LOADS(0);
  for (int e0 = 0; e0 < CDIM; e0 += 64) {
    // write P tile: 128 rows(m) x 64 e bf16, xor-swizzled granules
#pragma unroll
    for (int j = 0; j < 4; j++) {
      int c = cl + (j << 5);
      *(uint4*)(sP + c * 128 + (gs << 4)) = pr[j];
    }
    // write V^T tile: LDS row d (128 rows) holds 64 e as bf16 pairs
    {
      const float* p0 = (const float*)&vr[0]; const float* p1 = (const float*)&vr[1];
      const float* p2 = (const float*)&vr[2]; const float* p3 = (const float*)&vr[3];
      const float* p4 = (const float*)&vr[4]; const float* p5 = (const float*)&vr[5];
      const float* p6 = (const float*)&vr[6]; const float* p7 = (const float*)&vr[7];
#pragma unroll
      for (int dd = 0; dd < 4; dd++) {
        int d = (dg << 2) + dd;
        uint4 w;
        w.x = pack2bf(p0[dd], p1[dd]);
        w.y = pack2bf(p2[dd], p3[dd]);
        w.z = pack2bf(p4[dd], p5[dd]);
        w.w = pack2bf(p6[dd], p7[dd]);
        *(uint4*)(sV + d * 128 + ((vg ^ (d & 7)) << 4)) = w;
      }
    }
    __syncthreads();
    if (e0 + 64 < CDIM) PV_LOADS(e0 + 64);   // overlap with ds_read + MFMA below
#pragma unroll
    for (int kk = 0; kk < 2; kk++) {
      bf16x8 af[4], bfr[4];
#pragma unroll
      for (int mi = 0; mi < 4; mi++) {
        int r = wm * 64 + mi * 16 + l15;
        int g = kk * 4 + quad;
        af[mi] = *(const bf16x8*)(sP + r * 128 + ((g ^ (r & 7)) << 4));
      }
#pragma unroll
      for (int ni = 0; ni < 4; ni++) {
        int d = wn * 64 + ni * 16 + l15;
        int g = kk * 4 + quad;
        bfr[ni] = *(const bf16x8*)(sV + d * 128 + ((g ^ (d & 7)) << 4));
      }
#pragma unroll
      for (int mi = 0; mi < 4; mi++)
#pragma unroll
        for (int ni = 0; ni < 4; ni++)
          acc[mi][ni] = __builtin_amdgcn_mfma_f32_16x16x32_bf16(af[mi], bfr[ni], acc[mi][ni], 0, 0, 0);
    }
    __syncthreads();
  }
#undef PV_LOADS

#pragma unroll
  for (int mi = 0; mi < 4; mi++)
#pragma unroll
    for (int ni = 0; ni < 4; ni++) {
      int col = d0b + wn * 64 + ni * 16 + l15;
#pragma unroll
      for (int reg = 0; reg < 4; reg++) {
        int row = m0 + wm * 64 + mi * 16 + quad * 4 + reg;
        O[(size_t)row * DDIM + col] = acc[mi][ni][reg];
      }
    }
}

extern "C" void kernel_launch(void* const* d_in, const int* in_sizes, int n_in,
                              void* d_out, int out_size, void* d_ws, size_t ws_size,
                              hipStream_t stream) {
  (void)in_sizes; (void)n_in; (void)out_size; (void)ws_size;
  const float* x1 = (const float*)d_in[0];
  const float* x2 = (const float*)d_in[1];
  float* out = (float*)d_out;

  // d_out front 84 MiB: S partials (4 x 16.8 MiB fp32) + Ssum (16.8 MiB fp32).
  // Written by gemm_qk / softmax_rows, consumed by softmaxes, then overwritten
  // by gemm_pv (stream-ordered, so no hazard). d_ws holds only Pa/Pb (16 MiB).
  float*          S    = (float*)d_out;
  float*          Ssum = S + 4 * SPART;
  __hip_bfloat16* Pa   = (__hip_bfloat16*)d_ws;
  __hip_bfloat16* Pb   = (__hip_bfloat16*)((char*)d_ws + 8388608);

  gemm_qk<<<dim3(2, 2, BATCH * 4), 512, 0, stream>>>(x1, x2, S);
  softmax_rows<<<dim3(BATCH * CDIM), 256, 0, stream>>>(S, Ssum, Pa);
  softmax_cols<<<dim3(CDIM / 16, BATCH), 256, 0, stream>>>(Ssum, Pb);
  gemm_pv<<<dim3(DDIM / 128, CDIM / 128, BATCH * 2), 256, 0, stream>>>(Pa, Pb, x1, x2, out);
}